// Round 4
// baseline (801.408 us; speedup 1.0000x reference)
//
#include <hip/hip_runtime.h>
#include <hip/hip_bf16.h>

// Problem constants
#define NROWS 16384      // B*C = 32*512
#define DDIM  256        // H*W
#define KEMB  8192
#define DECAYF 0.99f
#define ONE_MINUS_DECAY 0.01f
#define EPSF 1e-5f

// Output layout (all float32, concatenated in return order)
#define O_QST   0
#define O_LOSS  4194304
#define O_IDX   4194305
#define O_EMB   4210689
#define O_ECS   6307841
#define O_EES   6316033

// Workspace layout (float offsets)
#define WS_NORMS 0          // 8192 floats
#define WS_KEY   8192       // 16384 x u64 (8B aligned: byte 32768)
#define WS_SCAL  57344      // [0]=loss_sum, [1]=0.99*sum(ecs_in)

typedef __attribute__((ext_vector_type(8))) short short8;
typedef __attribute__((ext_vector_type(4))) float f32x4;

// fp32 -> bf16 (RNE) as raw ushort, and back
static __device__ __forceinline__ unsigned short f2bf(float x) {
    unsigned int u = __float_as_uint(x);
    return (unsigned short)((u + 0x7fffu + ((u >> 16) & 1u)) >> 16);
}
static __device__ __forceinline__ float bf2f(unsigned short h) {
    return __uint_as_float(((unsigned int)h) << 16);
}

// async global->LDS, 16B per lane; lds base wave-uniform, lane i lands at +16*i
static __device__ __forceinline__ void gload16(const unsigned short* g, unsigned short* l) {
    __builtin_amdgcn_global_load_lds(
        (const __attribute__((address_space(1))) unsigned int*)g,
        (__attribute__((address_space(3))) unsigned int*)l, 16, 0, 0);
}

// ---------------- prep_e: one wave per code k ----------------
// e-norm (fp32 exact) + e hi/lo bf16 split + ecs/ees decay init + 0.99*sum(ecs)
__global__ __launch_bounds__(256) void prep_e(const float* __restrict__ emb,
                                              const float* __restrict__ ecs_in,
                                              const float* __restrict__ ees_in,
                                              float* __restrict__ enorm,
                                              unsigned short* __restrict__ eh,
                                              unsigned short* __restrict__ el,
                                              float* __restrict__ o_ecs,
                                              float* __restrict__ o_ees,
                                              float* __restrict__ scal) {
    const int k = blockIdx.x * 4 + (threadIdx.x >> 6);
    const int lane = threadIdx.x & 63;
    const int base = k * DDIM + lane * 4;
    const float4 v = *(const float4*)&emb[base];
    // hi/lo split
    ushort4 h, l;
    {
        const float* vp = (const float*)&v;
        unsigned short hh;
        hh = f2bf(vp[0]); h.x = hh; l.x = f2bf(vp[0] - bf2f(hh));
        hh = f2bf(vp[1]); h.y = hh; l.y = f2bf(vp[1] - bf2f(hh));
        hh = f2bf(vp[2]); h.z = hh; l.z = f2bf(vp[2] - bf2f(hh));
        hh = f2bf(vp[3]); h.w = hh; l.w = f2bf(vp[3] - bf2f(hh));
    }
    *(ushort4*)&eh[base] = h;
    *(ushort4*)&el[base] = l;
    // ees decay
    const float4 s = *(const float4*)&ees_in[base];
    float4 so;
    so.x = DECAYF * s.x; so.y = DECAYF * s.y; so.z = DECAYF * s.z; so.w = DECAYF * s.w;
    *(float4*)&o_ees[base] = so;
    // norm
    float sum = v.x * v.x + v.y * v.y + v.z * v.z + v.w * v.w;
    for (int o = 32; o; o >>= 1) sum += __shfl_down(sum, o);
    if (lane == 0) {
        enorm[k] = sum;
        const float c = DECAYF * ecs_in[k];
        o_ecs[k] = c;
        atomicAdd(&scal[1], c);
    }
}

// ---------------- prep_z: one wave per row ----------------
__global__ __launch_bounds__(256) void prep_z(const float* __restrict__ z,
                                              unsigned short* __restrict__ zh,
                                              unsigned short* __restrict__ zl,
                                              unsigned long long* __restrict__ key64) {
    const int n = blockIdx.x * 4 + (threadIdx.x >> 6);
    const int lane = threadIdx.x & 63;
    const int base = n * DDIM + lane * 4;
    const float4 v = *(const float4*)&z[base];
    ushort4 h, l;
    {
        const float* vp = (const float*)&v;
        unsigned short hh;
        hh = f2bf(vp[0]); h.x = hh; l.x = f2bf(vp[0] - bf2f(hh));
        hh = f2bf(vp[1]); h.y = hh; l.y = f2bf(vp[1] - bf2f(hh));
        hh = f2bf(vp[2]); h.z = hh; l.z = f2bf(vp[2] - bf2f(hh));
        hh = f2bf(vp[3]); h.w = hh; l.w = f2bf(vp[3] - bf2f(hh));
    }
    *(ushort4*)&zh[base] = h;
    *(ushort4*)&zl[base] = l;
    if (lane == 0) key64[n] = ~0ull;
}

// ---------------- argmin_mfma: bf16x3 GEMM + fused argmin ----------------
// Block 128x128, 4 waves (2x2 of 64x64). B (codes) staged in LDS via
// global_load_lds; A (z) fragments loaded DIRECTLY from global (fragment
// layout A[m=lane&15][k=quad*8+j] is 16B contiguous per lane).
__global__ __launch_bounds__(256) void argmin_mfma(const unsigned short* __restrict__ zh,
                                                   const unsigned short* __restrict__ zl,
                                                   const unsigned short* __restrict__ eh,
                                                   const unsigned short* __restrict__ el,
                                                   const float* __restrict__ enorm,
                                                   unsigned long long* __restrict__ key64) {
    __shared__ unsigned short Bh[128][32];   // pitch 64B: gload16-contiguous
    __shared__ unsigned short Bl[128][32];

    const int tid = threadIdx.x;
    const int lane = tid & 63;
    const int wid = tid >> 6;
    const int wm = wid >> 1, wn = wid & 1;
    const int tx = lane & 15, quad = lane >> 4;

    const int row0 = blockIdx.x * 128;
    const int col0 = blockIdx.y * 128;

    // B staging: wave w covers LDS rows [w*32, w*32+32); lane l -> row l>>2, 16B chunk l&3
    const int w32 = wid * 32;
    const int r16 = lane >> 2;
    const int c8 = (lane & 3) * 8;

    // A fragment base (per lane): row = row0 + wm*64 + tx (+mi*16), k = quad*8 (+dstep)
    const size_t abase = (size_t)(row0 + wm * 64 + tx) * DDIM + quad * 8;

    f32x4 acc[4][4];
#pragma unroll
    for (int i = 0; i < 4; i++)
#pragma unroll
        for (int j = 0; j < 4; j++) acc[i][j] = (f32x4){0.f, 0.f, 0.f, 0.f};

    for (int dstep = 0; dstep < DDIM; dstep += 32) {
        __syncthreads();   // all waves done reading previous B tile
        // B staging (async direct-to-LDS) + A fragment loads (to VGPR) in flight together
#pragma unroll
        for (int i = 0; i < 2; i++) {
            const int lr = w32 + i * 16;
            const size_t gb = (size_t)(col0 + lr + r16) * DDIM + dstep + c8;
            gload16(&eh[gb], &Bh[lr][0]);
            gload16(&el[gb], &Bl[lr][0]);
        }
        short8 aH[4], aL[4];
#pragma unroll
        for (int mi = 0; mi < 4; mi++) {
            aH[mi] = *(const short8*)(zh + abase + (size_t)mi * 16 * DDIM + dstep);
            aL[mi] = *(const short8*)(zl + abase + (size_t)mi * 16 * DDIM + dstep);
        }
        __syncthreads();   // drains vmcnt: B tile in LDS, A frags in regs

        short8 bH[4], bL[4];
        const int br = wn * 64 + tx;
#pragma unroll
        for (int nj = 0; nj < 4; nj++) {
            bH[nj] = *(const short8*)&Bh[br + nj * 16][quad * 8];
            bL[nj] = *(const short8*)&Bl[br + nj * 16][quad * 8];
        }
#pragma unroll
        for (int mi = 0; mi < 4; mi++)
#pragma unroll
            for (int nj = 0; nj < 4; nj++) {
                acc[mi][nj] = __builtin_amdgcn_mfma_f32_16x16x32_bf16(aH[mi], bH[nj], acc[mi][nj], 0, 0, 0);
                acc[mi][nj] = __builtin_amdgcn_mfma_f32_16x16x32_bf16(aL[mi], bH[nj], acc[mi][nj], 0, 0, 0);
                acc[mi][nj] = __builtin_amdgcn_mfma_f32_16x16x32_bf16(aH[mi], bL[nj], acc[mi][nj], 0, 0, 0);
            }
    }

    // epilogue: dist = ||e||^2 - 2 x.e ; fused argmin, k-ascending tie-break.
    // C/D layout: col = lane&15 (+nj*16), row = quad*4 + reg (+mi*16)
    float en[4];
    int colv[4];
#pragma unroll
    for (int nj = 0; nj < 4; nj++) {
        colv[nj] = col0 + wn * 64 + nj * 16 + tx;
        en[nj] = enorm[colv[nj]];
    }
#pragma unroll
    for (int mi = 0; mi < 4; mi++) {
#pragma unroll
        for (int r = 0; r < 4; r++) {
            unsigned long long best = ~0ull;
#pragma unroll
            for (int nj = 0; nj < 4; nj++) {
                float d = en[nj] - 2.0f * acc[mi][nj][r];
                unsigned int db = __float_as_uint(d);
                db = (db & 0x80000000u) ? ~db : (db | 0x80000000u);
                unsigned long long key = ((unsigned long long)db << 32) | (unsigned int)colv[nj];
                if (key < best) best = key;
            }
#pragma unroll
            for (int m = 1; m < 16; m <<= 1) {
                unsigned long long o = __shfl_xor(best, m);
                if (o < best) best = o;
            }
            if (tx == 0)
                atomicMin(&key64[row0 + wm * 64 + mi * 16 + quad * 4 + r], best);
        }
    }
}

// ---------------- quant_stats: decode idx + quantize + loss + EMA stats -----
__global__ __launch_bounds__(256) void quant_stats(const float* __restrict__ z,
                                                   const float* __restrict__ emb,
                                                   const unsigned long long* __restrict__ key64,
                                                   float* __restrict__ o_qst,
                                                   float* __restrict__ o_idx,
                                                   float* __restrict__ o_ecs,
                                                   float* __restrict__ o_ees,
                                                   float* __restrict__ scal) {
    const int n = (blockIdx.x * 256 + threadIdx.x) >> 6;   // one wave per row
    const int lane = threadIdx.x & 63;
    const int k = (int)(key64[n] & 0xFFFFFFFFull);
    const int d0 = lane * 4;
    const float4 zv = *(const float4*)&z[n * DDIM + d0];
    const float4 ev = *(const float4*)&emb[k * DDIM + d0];
    const float dx = ev.x - zv.x, dy = ev.y - zv.y, dz2 = ev.z - zv.z, dw = ev.w - zv.w;
    float4 q;
    q.x = zv.x + dx; q.y = zv.y + dy; q.z = zv.z + dz2; q.w = zv.w + dw;
    *(float4*)&o_qst[n * DDIM + d0] = q;
    float p = dx * dx + dy * dy + dz2 * dz2 + dw * dw;
    for (int o = 32; o; o >>= 1) p += __shfl_down(p, o);
    if (lane == 0) {
        o_idx[n] = (float)k;
        atomicAdd(&scal[0], p);
        atomicAdd(&o_ecs[k], ONE_MINUS_DECAY);
    }
    atomicAdd(&o_ees[k * DDIM + d0 + 0], ONE_MINUS_DECAY * zv.x);
    atomicAdd(&o_ees[k * DDIM + d0 + 1], ONE_MINUS_DECAY * zv.y);
    atomicAdd(&o_ees[k * DDIM + d0 + 2], ONE_MINUS_DECAY * zv.z);
    atomicAdd(&o_ees[k * DDIM + d0 + 3], ONE_MINUS_DECAY * zv.w);
}

// ---------------- finalize: new_embedding + loss scalar ----------------
// n_tot = sum(new_ecs) = 0.99*sum(ecs_in) + 0.01*NROWS  (scal[1] holds 1st term)
__global__ __launch_bounds__(256) void finalize_kernel(const float* __restrict__ o_ecs,
                                                       const float* __restrict__ o_ees,
                                                       const float* __restrict__ scal,
                                                       float* __restrict__ o_emb,
                                                       float* __restrict__ o_loss) {
    const int k = blockIdx.x;
    const int d = threadIdx.x;
    const float ntot = scal[1] + ONE_MINUS_DECAY * (float)NROWS;
    const float ecs = o_ecs[k];
    const float sm = (ecs + EPSF) / (ntot + (float)KEMB * EPSF) * ntot;
    o_emb[k * DDIM + d] = o_ees[k * DDIM + d] / sm;
    if (k == 0 && d == 0) o_loss[0] = 0.25f * scal[0] / (float)(NROWS * DDIM);
}

extern "C" void kernel_launch(void* const* d_in, const int* in_sizes, int n_in,
                              void* d_out, int out_size, void* d_ws, size_t ws_size,
                              hipStream_t stream) {
    const float* z   = (const float*)d_in[0];
    const float* emb = (const float*)d_in[1];
    const float* ecs = (const float*)d_in[2];
    const float* ees = (const float*)d_in[3];

    float* out = (float*)d_out;
    float* ws  = (float*)d_ws;

    float* enorm = ws + WS_NORMS;
    unsigned long long* key64 = (unsigned long long*)(ws + WS_KEY);
    float* scal  = ws + WS_SCAL;

    // bf16 hi/lo scratch lives in output regions overwritten later:
    // z hi+lo (16 MB) in O_QST (16.77 MB); e hi+lo (8 MB) in O_EMB (8 MB exact)
    unsigned short* zh = (unsigned short*)(out + O_QST);
    unsigned short* zl = zh + NROWS * DDIM;
    unsigned short* ehp = (unsigned short*)(out + O_EMB);
    unsigned short* elp = ehp + KEMB * DDIM;

    hipMemsetAsync(scal, 0, 2 * sizeof(float), stream);
    prep_e<<<KEMB / 4, 256, 0, stream>>>(emb, ecs, ees, enorm, ehp, elp,
                                         out + O_ECS, out + O_EES, scal);
    prep_z<<<NROWS / 4, 256, 0, stream>>>(z, zh, zl, key64);
    argmin_mfma<<<dim3(NROWS / 128, KEMB / 128), 256, 0, stream>>>(zh, zl, ehp, elp, enorm, key64);
    quant_stats<<<(NROWS * 64) / 256, 256, 0, stream>>>(z, emb, key64, out + O_QST, out + O_IDX,
                                                        out + O_ECS, out + O_EES, scal);
    finalize_kernel<<<KEMB, DDIM, 0, stream>>>(out + O_ECS, out + O_EES, scal,
                                               out + O_EMB, out + O_LOSS);
}

// Round 5
// 567.121 us; speedup vs baseline: 1.4131x; 1.4131x over previous
//
#include <hip/hip_runtime.h>
#include <hip/hip_bf16.h>

// Problem constants
#define NROWS 16384      // B*C = 32*512
#define DDIM  256        // H*W
#define KEMB  8192
#define DECAYF 0.99f
#define ONE_MINUS_DECAY 0.01f
#define EPSF 1e-5f

// Output layout (all float32, concatenated in return order)
#define O_QST   0
#define O_LOSS  4194304
#define O_IDX   4194305
#define O_EMB   4210689
#define O_ECS   6307841
#define O_EES   6316033

typedef __attribute__((ext_vector_type(8))) short short8;
typedef __attribute__((ext_vector_type(4))) float f32x4;

// fp32 -> bf16 (RNE) as raw ushort, and back
static __device__ __forceinline__ unsigned short f2bf(float x) {
    unsigned int u = __float_as_uint(x);
    return (unsigned short)((u + 0x7fffu + ((u >> 16) & 1u)) >> 16);
}
static __device__ __forceinline__ float bf2f(unsigned short h) {
    return __uint_as_float(((unsigned int)h) << 16);
}

// async global->LDS, 16B per lane; lds base wave-uniform, lane i lands at +16*i
static __device__ __forceinline__ void gload16(const unsigned short* g, unsigned short* l) {
    __builtin_amdgcn_global_load_lds(
        (const __attribute__((address_space(1))) unsigned int*)g,
        (__attribute__((address_space(3))) unsigned int*)l, 16, 0, 0);
}

// ---------------- prep_e: one wave per code k ----------------
// e-norm (fp32 exact) + e hi/lo bf16 split + ecs/ees decay init
__global__ __launch_bounds__(256) void prep_e(const float* __restrict__ emb,
                                              const float* __restrict__ ecs_in,
                                              const float* __restrict__ ees_in,
                                              float* __restrict__ enorm,
                                              unsigned short* __restrict__ eh,
                                              unsigned short* __restrict__ el,
                                              float* __restrict__ o_ecs,
                                              float* __restrict__ o_ees) {
    const int k = blockIdx.x * 4 + (threadIdx.x >> 6);
    const int lane = threadIdx.x & 63;
    const int base = k * DDIM + lane * 4;
    const float4 v = *(const float4*)&emb[base];
    ushort4 h, l;
    {
        const float* vp = (const float*)&v;
        unsigned short hh;
        hh = f2bf(vp[0]); h.x = hh; l.x = f2bf(vp[0] - bf2f(hh));
        hh = f2bf(vp[1]); h.y = hh; l.y = f2bf(vp[1] - bf2f(hh));
        hh = f2bf(vp[2]); h.z = hh; l.z = f2bf(vp[2] - bf2f(hh));
        hh = f2bf(vp[3]); h.w = hh; l.w = f2bf(vp[3] - bf2f(hh));
    }
    *(ushort4*)&eh[base] = h;
    *(ushort4*)&el[base] = l;
    const float4 s = *(const float4*)&ees_in[base];
    float4 so;
    so.x = DECAYF * s.x; so.y = DECAYF * s.y; so.z = DECAYF * s.z; so.w = DECAYF * s.w;
    *(float4*)&o_ees[base] = so;
    float sum = v.x * v.x + v.y * v.y + v.z * v.z + v.w * v.w;
    for (int o = 32; o; o >>= 1) sum += __shfl_down(sum, o);
    if (lane == 0) {
        enorm[k] = sum;
        o_ecs[k] = DECAYF * ecs_in[k];
    }
}

// ---------------- prep_z: one wave per row ----------------
__global__ __launch_bounds__(256) void prep_z(const float* __restrict__ z,
                                              unsigned short* __restrict__ zh,
                                              unsigned short* __restrict__ zl,
                                              unsigned long long* __restrict__ key64) {
    const int n = blockIdx.x * 4 + (threadIdx.x >> 6);
    const int lane = threadIdx.x & 63;
    const int base = n * DDIM + lane * 4;
    const float4 v = *(const float4*)&z[base];
    ushort4 h, l;
    {
        const float* vp = (const float*)&v;
        unsigned short hh;
        hh = f2bf(vp[0]); h.x = hh; l.x = f2bf(vp[0] - bf2f(hh));
        hh = f2bf(vp[1]); h.y = hh; l.y = f2bf(vp[1] - bf2f(hh));
        hh = f2bf(vp[2]); h.z = hh; l.z = f2bf(vp[2] - bf2f(hh));
        hh = f2bf(vp[3]); h.w = hh; l.w = f2bf(vp[3] - bf2f(hh));
    }
    *(ushort4*)&zh[base] = h;
    *(ushort4*)&zl[base] = l;
    if (lane == 0) key64[n] = ~0ull;
}

// ---------------- sum_ecs: single block; scal[1]=0.99*sum(ecs), scal[0]=0 ---
__global__ __launch_bounds__(256) void sum_ecs(const float* __restrict__ ecs_in,
                                               float* __restrict__ scal) {
    float s = 0.f;
    for (int i = threadIdx.x; i < KEMB; i += 256) s += ecs_in[i];
    for (int o = 32; o; o >>= 1) s += __shfl_down(s, o);
    __shared__ float sh[4];
    if ((threadIdx.x & 63) == 0) sh[threadIdx.x >> 6] = s;
    __syncthreads();
    if (threadIdx.x == 0) {
        scal[1] = DECAYF * (sh[0] + sh[1] + sh[2] + sh[3]);
        scal[0] = 0.f;
    }
}

// ---------------- argmin_mfma: bf16x3 GEMM + fused argmin ----------------
// Block 256x128, 4 waves 2x2; per-wave tile 128x64 (acc 8x4) to cut LDS
// bytes per MFMA (ratio ~2.5:1 vs 3.3:1 at 64x64). Both operands staged
// via global_load_lds width=16.
__global__ __launch_bounds__(256) void argmin_mfma(const unsigned short* __restrict__ zh,
                                                   const unsigned short* __restrict__ zl,
                                                   const unsigned short* __restrict__ eh,
                                                   const unsigned short* __restrict__ el,
                                                   const float* __restrict__ enorm,
                                                   unsigned long long* __restrict__ key64) {
    __shared__ unsigned short Ah[256][32];   // 16 KB
    __shared__ unsigned short Al[256][32];   // 16 KB
    __shared__ unsigned short Bh[128][32];   // 8 KB
    __shared__ unsigned short Bl[128][32];   // 8 KB

    const int tid = threadIdx.x;
    const int lane = tid & 63;
    const int wid = tid >> 6;
    const int wm = wid >> 1, wn = wid & 1;
    const int tx = lane & 15, quad = lane >> 4;

    const int row0 = blockIdx.x * 256;
    const int col0 = blockIdx.y * 128;

    // staging: wave w -> A rows [w*64, w*64+64), B rows [w*32, w*32+32)
    const int aw = wid * 64;
    const int bw = wid * 32;
    const int r16 = lane >> 2;
    const int c8 = (lane & 3) * 8;

    f32x4 acc[8][4];
#pragma unroll
    for (int i = 0; i < 8; i++)
#pragma unroll
        for (int j = 0; j < 4; j++) acc[i][j] = (f32x4){0.f, 0.f, 0.f, 0.f};

    for (int dstep = 0; dstep < DDIM; dstep += 32) {
        __syncthreads();   // all waves done reading previous tiles
#pragma unroll
        for (int i = 0; i < 4; i++) {
            const int lr = aw + i * 16;
            const size_t ga = (size_t)(row0 + lr + r16) * DDIM + dstep + c8;
            gload16(&zh[ga], &Ah[lr][0]);
            gload16(&zl[ga], &Al[lr][0]);
        }
#pragma unroll
        for (int i = 0; i < 2; i++) {
            const int lr = bw + i * 16;
            const size_t gb = (size_t)(col0 + lr + r16) * DDIM + dstep + c8;
            gload16(&eh[gb], &Bh[lr][0]);
            gload16(&el[gb], &Bl[lr][0]);
        }
        __syncthreads();   // drains vmcnt: tiles resident

        short8 bH[4], bL[4];
        const int br = wn * 64 + tx;
#pragma unroll
        for (int nj = 0; nj < 4; nj++) {
            bH[nj] = *(const short8*)&Bh[br + nj * 16][quad * 8];
            bL[nj] = *(const short8*)&Bl[br + nj * 16][quad * 8];
        }
        const int ar = wm * 128 + tx;
#pragma unroll
        for (int mi = 0; mi < 8; mi++) {
            const short8 aH = *(const short8*)&Ah[ar + mi * 16][quad * 8];
            const short8 aL = *(const short8*)&Al[ar + mi * 16][quad * 8];
#pragma unroll
            for (int nj = 0; nj < 4; nj++) {
                acc[mi][nj] = __builtin_amdgcn_mfma_f32_16x16x32_bf16(aH, bH[nj], acc[mi][nj], 0, 0, 0);
                acc[mi][nj] = __builtin_amdgcn_mfma_f32_16x16x32_bf16(aL, bH[nj], acc[mi][nj], 0, 0, 0);
                acc[mi][nj] = __builtin_amdgcn_mfma_f32_16x16x32_bf16(aH, bL[nj], acc[mi][nj], 0, 0, 0);
            }
        }
    }

    // epilogue: dist = ||e||^2 - 2 x.e ; fused argmin, k-ascending tie-break.
    // C/D layout: col = lane&15 (+nj*16), row = quad*4 + reg (+mi*16)
    float en[4];
    int colv[4];
#pragma unroll
    for (int nj = 0; nj < 4; nj++) {
        colv[nj] = col0 + wn * 64 + nj * 16 + tx;
        en[nj] = enorm[colv[nj]];
    }
#pragma unroll
    for (int mi = 0; mi < 8; mi++) {
#pragma unroll
        for (int r = 0; r < 4; r++) {
            unsigned long long best = ~0ull;
#pragma unroll
            for (int nj = 0; nj < 4; nj++) {
                float d = en[nj] - 2.0f * acc[mi][nj][r];
                unsigned int db = __float_as_uint(d);
                db = (db & 0x80000000u) ? ~db : (db | 0x80000000u);
                unsigned long long key = ((unsigned long long)db << 32) | (unsigned int)colv[nj];
                if (key < best) best = key;
            }
#pragma unroll
            for (int m = 1; m < 16; m <<= 1) {
                unsigned long long o = __shfl_xor(best, m);
                if (o < best) best = o;
            }
            if (tx == 0)
                atomicMin(&key64[row0 + wm * 128 + mi * 16 + quad * 4 + r], best);
        }
    }
}

// ---------------- quant_stats: 4 rows per wave, block-reduced loss ----------
__global__ __launch_bounds__(256) void quant_stats(const float* __restrict__ z,
                                                   const float* __restrict__ emb,
                                                   const unsigned long long* __restrict__ key64,
                                                   float* __restrict__ o_qst,
                                                   float* __restrict__ o_idx,
                                                   float* __restrict__ o_ecs,
                                                   float* __restrict__ o_ees,
                                                   float* __restrict__ scal) {
    const int w = threadIdx.x >> 6;
    const int lane = threadIdx.x & 63;
    const int nbase = blockIdx.x * 16 + w * 4;
    const int d0 = lane * 4;
    float ploc = 0.f;
#pragma unroll
    for (int r = 0; r < 4; r++) {
        const int n = nbase + r;
        const int k = (int)(key64[n] & 0xFFFFFFFFull);
        const float4 zv = *(const float4*)&z[n * DDIM + d0];
        const float4 ev = *(const float4*)&emb[k * DDIM + d0];
        const float dx = ev.x - zv.x, dy = ev.y - zv.y, dz2 = ev.z - zv.z, dw = ev.w - zv.w;
        float4 q;
        q.x = zv.x + dx; q.y = zv.y + dy; q.z = zv.z + dz2; q.w = zv.w + dw;
        *(float4*)&o_qst[n * DDIM + d0] = q;
        ploc += dx * dx + dy * dy + dz2 * dz2 + dw * dw;
        if (lane == 0) {
            o_idx[n] = (float)k;
            atomicAdd(&o_ecs[k], ONE_MINUS_DECAY);
        }
        atomicAdd(&o_ees[k * DDIM + d0 + 0], ONE_MINUS_DECAY * zv.x);
        atomicAdd(&o_ees[k * DDIM + d0 + 1], ONE_MINUS_DECAY * zv.y);
        atomicAdd(&o_ees[k * DDIM + d0 + 2], ONE_MINUS_DECAY * zv.z);
        atomicAdd(&o_ees[k * DDIM + d0 + 3], ONE_MINUS_DECAY * zv.w);
    }
    for (int o = 32; o; o >>= 1) ploc += __shfl_down(ploc, o);
    __shared__ float sh[4];
    if (lane == 0) sh[w] = ploc;
    __syncthreads();
    if (threadIdx.x == 0) atomicAdd(&scal[0], sh[0] + sh[1] + sh[2] + sh[3]);
}

// ---------------- finalize: new_embedding + loss scalar ----------------
// n_tot = 0.99*sum(ecs_in) + 0.01*NROWS   (scal[1] holds first term)
__global__ __launch_bounds__(256) void finalize_kernel(const float* __restrict__ o_ecs,
                                                       const float* __restrict__ o_ees,
                                                       const float* __restrict__ scal,
                                                       float* __restrict__ o_emb,
                                                       float* __restrict__ o_loss) {
    const int k = blockIdx.x;
    const int d = threadIdx.x;
    const float ntot = scal[1] + ONE_MINUS_DECAY * (float)NROWS;
    const float ecs = o_ecs[k];
    const float sm = (ecs + EPSF) / (ntot + (float)KEMB * EPSF) * ntot;
    o_emb[k * DDIM + d] = o_ees[k * DDIM + d] / sm;
    if (k == 0 && d == 0) o_loss[0] = 0.25f * scal[0] / (float)(NROWS * DDIM);
}

extern "C" void kernel_launch(void* const* d_in, const int* in_sizes, int n_in,
                              void* d_out, int out_size, void* d_ws, size_t ws_size,
                              hipStream_t stream) {
    const float* z   = (const float*)d_in[0];
    const float* emb = (const float*)d_in[1];
    const float* ecs = (const float*)d_in[2];
    const float* ees = (const float*)d_in[3];

    float* out = (float*)d_out;
    char*  ws  = (char*)d_ws;

    // small scratch at head of ws: norms (32KB), key64 (128KB), scal (8B)
    float* enorm = (float*)ws;                                    // 8192 f
    unsigned long long* key64 = (unsigned long long*)(ws + 32768);// 16384 u64
    float* scal = (float*)(ws + 32768 + 131072);

    // bf16 hi/lo scratch: prefer d_ws if large enough, else alias output
    // regions that are overwritten later (zh/zl in O_QST, eh/el in O_EMB).
    const size_t big0 = 32768 + 131072 + 256;                     // 164 KB
    const size_t bigbytes = (size_t)(NROWS + KEMB) * DDIM * 2 * 2;// 24 MB
    unsigned short *zh, *zl, *ehp, *elp;
    if (ws_size >= big0 + bigbytes) {
        zh  = (unsigned short*)(ws + big0);
        zl  = zh + NROWS * DDIM;
        ehp = zl + NROWS * DDIM;
        elp = ehp + KEMB * DDIM;
    } else {
        zh  = (unsigned short*)(out + O_QST);
        zl  = zh + NROWS * DDIM;
        ehp = (unsigned short*)(out + O_EMB);
        elp = ehp + KEMB * DDIM;
    }

    prep_e<<<KEMB / 4, 256, 0, stream>>>(emb, ecs, ees, enorm, ehp, elp,
                                         out + O_ECS, out + O_EES);
    prep_z<<<NROWS / 4, 256, 0, stream>>>(z, zh, zl, key64);
    sum_ecs<<<1, 256, 0, stream>>>(ecs, scal);
    argmin_mfma<<<dim3(NROWS / 256, KEMB / 128), 256, 0, stream>>>(zh, zl, ehp, elp, enorm, key64);
    quant_stats<<<NROWS / 16, 256, 0, stream>>>(z, emb, key64, out + O_QST, out + O_IDX,
                                                out + O_ECS, out + O_EES, scal);
    finalize_kernel<<<KEMB, DDIM, 0, stream>>>(out + O_ECS, out + O_EES, scal,
                                               out + O_EMB, out + O_LOSS);
}